// Round 1
// baseline (3956.660 us; speedup 1.0000x reference)
//
#include <hip/hip_runtime.h>
#include <cmath>

// ---------------------------------------------------------------------------
// Sizes (fixed for this problem)
// ---------------------------------------------------------------------------
#define T_  64
#define B_  256
#define D_  2000
#define TN_ 3000
#define E_  256
#define H_  256
#define A_  128
#define V_  128
#define PS_ 64
#define PE_ 64
#define S_  128
#define G1N_ 1500
#define G1L_ 4
#define G2N_ 1500
#define G2L_ 6
#define M_  (T_ * B_)          // 16384 rows for all [T,B,*] GEMMs
#define KF_ (H_ + V_ + PE_)    // 448 final concat width

static __device__ __forceinline__ float sigmoidf_(float x) {
    return 1.0f / (1.0f + __expf(-x));
}

// ---------------------------------------------------------------------------
// Generic tiled fp32 GEMM:  C[M,N] = A[M,K] @ B[K,N] (+bias) (+epilogue)
// AMODE 0: plain A (lda=K). AMODE 1: concat A = [A (lda=K1) | A2[(m%256), k-K1]]
// EPI 0: none. EPI 1: sigmoid on n<N/2, tanh on n>=N/2 (erase|add).
// block = (BN/TN, BM/TM) = (16,16) = 256 threads
// ---------------------------------------------------------------------------
template<int BM, int BN, int BK, int TM, int TN, int AMODE, int EPI>
__global__ __launch_bounds__(256)
void k_gemm(const float* __restrict__ A, const float* __restrict__ B,
            const float* __restrict__ bias, float* __restrict__ C,
            int M, int N, int K, const float* __restrict__ A2, int K1)
{
    __shared__ float As[BK][BM + 4];
    __shared__ float Bs[BK][BN + 4];

    const int tid = threadIdx.y * blockDim.x + threadIdx.x;
    const int m0 = blockIdx.y * BM;
    const int n0 = blockIdx.x * BN;

    float acc[TM][TN];
#pragma unroll
    for (int i = 0; i < TM; ++i)
#pragma unroll
        for (int j = 0; j < TN; ++j) acc[i][j] = 0.0f;

    for (int k0 = 0; k0 < K; k0 += BK) {
        // load A tile (BM x BK)
#pragma unroll
        for (int i = tid; i < BM * BK; i += 256) {
            int r = i / BK, c = i % BK;
            int m = m0 + r, k = k0 + c;
            float v = 0.0f;
            if (m < M) {
                if (AMODE == 0) {
                    v = A[(size_t)m * K + k];
                } else {
                    v = (k < K1) ? A[(size_t)m * K1 + k]
                                 : A2[(size_t)(m & (B_ - 1)) * (K - K1) + (k - K1)];
                }
            }
            As[c][r] = v;
        }
        // load B tile (BK x BN)
#pragma unroll
        for (int i = tid; i < BK * BN; i += 256) {
            int r = i / BN, c = i % BN;
            int n = n0 + c;
            Bs[r][c] = (n < N) ? B[(size_t)(k0 + r) * N + n] : 0.0f;
        }
        __syncthreads();

#pragma unroll
        for (int kk = 0; kk < BK; ++kk) {
            float a[TM], b[TN];
#pragma unroll
            for (int i = 0; i < TM; ++i) a[i] = As[kk][threadIdx.y * TM + i];
#pragma unroll
            for (int j = 0; j < TN; ++j) b[j] = Bs[kk][threadIdx.x * TN + j];
#pragma unroll
            for (int i = 0; i < TM; ++i)
#pragma unroll
                for (int j = 0; j < TN; ++j) acc[i][j] += a[i] * b[j];
        }
        __syncthreads();
    }

#pragma unroll
    for (int i = 0; i < TM; ++i) {
        int m = m0 + threadIdx.y * TM + i;
        if (m >= M) continue;
#pragma unroll
        for (int j = 0; j < TN; ++j) {
            int n = n0 + threadIdx.x * TN + j;
            if (n >= N) continue;
            float v = acc[i][j];
            if (bias) v += bias[n];
            if (EPI == 1) v = (n < (N >> 1)) ? sigmoidf_(v) : tanhf(v);
            C[(size_t)m * N + n] = v;
        }
    }
}

// ---------------------------------------------------------------------------
// Small prep kernels
// ---------------------------------------------------------------------------
// W2[e][j] : j<128 -> Wa_w[e][j] ; j>=128 -> Wa_w[256+e][j-128]
__global__ void k_pack_w2(const float* __restrict__ Wa_w, float* __restrict__ W2)
{
    int idx = blockIdx.x * blockDim.x + threadIdx.x;
    if (idx >= E_ * 2 * A_) return;
    int e = idx / (2 * A_), j = idx % (2 * A_);
    W2[idx] = (j < A_) ? Wa_w[(size_t)e * A_ + j]
                       : Wa_w[(size_t)(E_ + e) * A_ + (j - A_)];
}

// Wea[k][n]: n<128 erase_w[k][n] else add_w[k][n-128]; bea likewise
__global__ void k_pack_wea(const float* __restrict__ erase_w, const float* __restrict__ add_w,
                           const float* __restrict__ erase_b, const float* __restrict__ add_b,
                           float* __restrict__ Wea, float* __restrict__ bea)
{
    int idx = blockIdx.x * blockDim.x + threadIdx.x;
    if (idx < E_ * 2 * V_) {
        int k = idx / (2 * V_), n = idx % (2 * V_);
        Wea[idx] = (n < V_) ? erase_w[(size_t)k * V_ + n]
                            : add_w[(size_t)k * V_ + (n - V_)];
    }
    if (idx < 2 * V_) bea[idx] = (idx < V_) ? erase_b[idx] : add_b[idx - V_];
}

// generic transpose: src[R][C] -> dst[C][R]
__global__ void k_transpose(const float* __restrict__ src, float* __restrict__ dst, int R, int C)
{
    int idx = blockIdx.x * blockDim.x + threadIdx.x;
    if (idx >= R * C) return;
    int r = idx / C, c = idx % C;
    dst[(size_t)c * R + r] = src[idx];
}

// KMT[e][s] = ini_embd[KMIds[s]][e]
__global__ void k_kmt(const float* __restrict__ ini_embd, const int* __restrict__ KMIds,
                      float* __restrict__ KMT)
{
    int idx = blockIdx.x * blockDim.x + threadIdx.x;
    if (idx >= E_ * S_) return;
    int e = idx / S_, s = idx % S_;
    KMT[idx] = ini_embd[(size_t)KMIds[s] * E_ + e];
}

// embedMat[d][e] = embedG[mapInfo[d]][e]
__global__ void k_gather_embed(const float* __restrict__ embedG, const int* __restrict__ mapInfo,
                               float* __restrict__ embedMat)
{
    int idx = blockIdx.x * blockDim.x + threadIdx.x;
    if (idx >= D_ * E_) return;
    int d = idx / E_, e = idx % E_;
    embedMat[idx] = embedG[(size_t)mapInfo[d] * E_ + e];
}

// prof[b][j] = profiles[b] @ emP_w + emP_b   (block=64, grid=B)
__global__ void k_prof(const float* __restrict__ profiles, const float* __restrict__ emP_w,
                       const float* __restrict__ emP_b, float* __restrict__ prof)
{
    int b = blockIdx.x, j = threadIdx.x;
    float acc = emP_b[j];
    for (int k = 0; k < PS_; ++k) acc += profiles[(size_t)b * PS_ + k] * emP_w[(size_t)k * PE_ + j];
    prof[(size_t)b * PE_ + j] = acc;
}

// ---------------------------------------------------------------------------
// Group embedding (GRAM attention): block=64 (one wave), grid = G1N+G2N
// PP[t][0:128]=P1 row, PP[t][128:256]=P2 row
// ---------------------------------------------------------------------------
__global__ void k_group_embed(const float* __restrict__ PP, const float* __restrict__ Wa_b,
                              const float* __restrict__ Ua_w, const float* __restrict__ ini_embd,
                              const int* __restrict__ leaves1, const int* __restrict__ anc1,
                              const int* __restrict__ leaves2, const int* __restrict__ anc2,
                              float* __restrict__ embedG)
{
    int n = blockIdx.x;
    int lane = threadIdx.x;
    const int* lv; const int* ac; int L;
    if (n < G1N_) { L = G1L_; lv = leaves1 + (size_t)n * G1L_; ac = anc1 + (size_t)n * G1L_; }
    else { int n2 = n - G1N_; L = G2L_; lv = leaves2 + (size_t)n2 * G2L_; ac = anc2 + (size_t)n2 * G2L_; }

    float score[6]; int ai[6];
    for (int l = 0; l < L; ++l) {
        int li = lv[l]; int av = ac[l]; ai[l] = av;
        float s = 0.0f;
        for (int a = lane; a < A_; a += 64) {
            float hv = tanhf(PP[(size_t)li * 256 + a] + PP[(size_t)av * 256 + 128 + a] + Wa_b[a]);
            s += hv * Ua_w[a];
        }
        for (int o = 32; o; o >>= 1) s += __shfl_xor(s, o);
        score[l] = s;
    }
    float mx = -1e30f;
    for (int l = 0; l < L; ++l) mx = fmaxf(mx, score[l]);
    float w[6], sum = 0.0f;
    for (int l = 0; l < L; ++l) { w[l] = __expf(score[l] - mx); sum += w[l]; }
    float inv = 1.0f / sum;
    for (int e = lane; e < E_; e += 64) {
        float acc = 0.0f;
        for (int l = 0; l < L; ++l) acc += w[l] * inv * ini_embd[(size_t)ai[l] * E_ + e];
        embedG[(size_t)n * E_ + e] = acc;
    }
}

// ---------------------------------------------------------------------------
// GRU scan: 64 workgroups x 256 threads; 4 batch samples per wg; h in LDS.
// gx precomputed (includes bih). WhhT[e][j] pre-transposed, coalesced reads.
// ---------------------------------------------------------------------------
__global__ __launch_bounds__(256)
void k_gru(const float* __restrict__ gx, const float* __restrict__ WhhT,
           const float* __restrict__ bhh, const int* __restrict__ X_len,
           float* __restrict__ gru_out)
{
    const int wg = blockIdx.x;
    const int s0 = wg * 4;
    const int tid = threadIdx.x;
    __shared__ float h[4][H_];

#pragma unroll
    for (int s = 0; s < 4; ++s) h[s][tid] = 0.0f;
    int len[4];
#pragma unroll
    for (int s = 0; s < 4; ++s) len[s] = X_len[s0 + s];
    __syncthreads();

    const float b0 = bhh[tid], b1 = bhh[256 + tid], b2 = bhh[512 + tid];

    for (int t = 0; t < T_; ++t) {
        float acc[4][3];
#pragma unroll
        for (int s = 0; s < 4; ++s) { acc[s][0] = b0; acc[s][1] = b1; acc[s][2] = b2; }

#pragma unroll 4
        for (int e = 0; e < H_; ++e) {
            const float* wr = WhhT + (size_t)e * (3 * H_);
            float w0 = wr[tid], w1 = wr[256 + tid], w2 = wr[512 + tid];
            float h0 = h[0][e], h1 = h[1][e], h2 = h[2][e], h3 = h[3][e];
            acc[0][0] += h0 * w0; acc[0][1] += h0 * w1; acc[0][2] += h0 * w2;
            acc[1][0] += h1 * w0; acc[1][1] += h1 * w1; acc[1][2] += h1 * w2;
            acc[2][0] += h2 * w0; acc[2][1] += h2 * w1; acc[2][2] += h2 * w2;
            acc[3][0] += h3 * w0; acc[3][1] += h3 * w1; acc[3][2] += h3 * w2;
        }

        float hst[4], ost[4];
#pragma unroll
        for (int s = 0; s < 4; ++s) {
            size_t gb = ((size_t)t * B_ + (s0 + s)) * (3 * H_);
            float gr = gx[gb + tid];
            float gz = gx[gb + 256 + tid];
            float gn = gx[gb + 512 + tid];
            float r = sigmoidf_(gr + acc[s][0]);
            float z = sigmoidf_(gz + acc[s][1]);
            float nn = tanhf(gn + r * acc[s][2]);
            float hold = h[s][tid];
            float hnew = (1.0f - z) * nn + z * hold;
            bool msk = (t < len[s]);
            float hv = msk ? hnew : hold;
            hst[s] = hv;
            ost[s] = msk ? hv : 0.0f;
        }
        __syncthreads();
#pragma unroll
        for (int s = 0; s < 4; ++s) {
            h[s][tid] = hst[s];
            gru_out[((size_t)t * B_ + (s0 + s)) * H_ + tid] = ost[s];
        }
        __syncthreads();
    }
}

// ---------------------------------------------------------------------------
// Value-memory scan: grid=B (one wg per sample), block=256.
// Thread owns v = tid&127, s-half = tid>>7 -> 64 VM values in registers.
// ---------------------------------------------------------------------------
__global__ __launch_bounds__(256)
void k_mem(const float* __restrict__ slotw, const float* __restrict__ era,
           const float* __restrict__ iniVam, float* __restrict__ readv)
{
    const int b = blockIdx.x;
    const int tid = threadIdx.x;
    const int v = tid & (V_ - 1);
    const int sh = tid >> 7;
    const int sbase = sh * 64;

    float VM[64];
#pragma unroll 8
    for (int i = 0; i < 64; ++i) VM[i] = iniVam[(size_t)(sbase + i) * V_ + v];

    __shared__ float swL[S_];
    __shared__ float eaL[2 * V_];
    __shared__ float part[V_];

    for (int t = 0; t < T_; ++t) {
        size_t m = (size_t)t * B_ + b;
        if (tid < S_) swL[tid] = slotw[m * S_ + tid];
        eaL[tid] = era[m * (2 * V_) + tid];
        __syncthreads();

        float er = eaL[v], ad = eaL[V_ + v];
        float acc = 0.0f;
#pragma unroll 8
        for (int i = 0; i < 64; ++i) {
            float sv = swL[sbase + i];
            float vm = VM[i];
            acc += sv * vm;
            float t1 = sv * er;
            float t2 = sv * ad;
            VM[i] = vm * (1.0f - t1) + t2;
        }
        if (sh == 1) part[v] = acc;
        __syncthreads();
        if (sh == 0) readv[m * V_ + v] = acc + part[v];
        __syncthreads();
    }
}

// ---------------------------------------------------------------------------
// Build F = [gru_out | read | prof2] rows; prof2 = prof * relu(concat(prof,read)@attnP)
// grid = M_, block = 256
// ---------------------------------------------------------------------------
__global__ __launch_bounds__(256)
void k_build_final(const float* __restrict__ gru_out, const float* __restrict__ readv,
                   const float* __restrict__ prof, const float* __restrict__ attnP_w,
                   const float* __restrict__ attnP_b, float* __restrict__ F)
{
    const int m = blockIdx.x;
    const int b = m & (B_ - 1);
    const int tid = threadIdx.x;
    __shared__ float rd[V_];
    __shared__ float pf[PE_];
    if (tid < V_) rd[tid] = readv[(size_t)m * V_ + tid];
    if (tid < PE_) pf[tid] = prof[(size_t)b * PE_ + tid];
    __syncthreads();

    F[(size_t)m * KF_ + tid] = gru_out[(size_t)m * H_ + tid];
    if (tid < V_) F[(size_t)m * KF_ + H_ + tid] = rd[tid];
    if (tid < PE_) {
        float a = attnP_b[tid];
        for (int k = 0; k < PE_; ++k) a += pf[k] * attnP_w[(size_t)k * PE_ + tid];
        for (int k = 0; k < V_; ++k) a += rd[k] * attnP_w[(size_t)(PE_ + k) * PE_ + tid];
        a = fmaxf(a, 0.0f);
        F[(size_t)m * KF_ + H_ + V_ + tid] = pf[tid] * a;
    }
}

// ---------------------------------------------------------------------------
// In-place row softmax over N=128 (block=64) and N=2000 (block=256)
// ---------------------------------------------------------------------------
__global__ void k_softmax128(float* __restrict__ C)
{
    const int m = blockIdx.x;
    const size_t base = (size_t)m * S_;
    const int lane = threadIdx.x;
    float a = C[base + lane], b = C[base + 64 + lane];
    float mx = fmaxf(a, b);
    for (int o = 32; o; o >>= 1) mx = fmaxf(mx, __shfl_xor(mx, o));
    float e0 = __expf(a - mx), e1 = __expf(b - mx);
    float s = e0 + e1;
    for (int o = 32; o; o >>= 1) s += __shfl_xor(s, o);
    float inv = 1.0f / s;
    C[base + lane] = e0 * inv;
    C[base + 64 + lane] = e1 * inv;
}

__global__ __launch_bounds__(256)
void k_softmax_rows(float* __restrict__ C, int N)
{
    const int m = blockIdx.x;
    const size_t base = (size_t)m * N;
    const int tid = threadIdx.x;
    const int wid = tid >> 6, lane = tid & 63;
    __shared__ float red[4], red2[4];

    float mx = -1e30f;
    for (int d = tid; d < N; d += 256) mx = fmaxf(mx, C[base + d]);
    for (int o = 32; o; o >>= 1) mx = fmaxf(mx, __shfl_xor(mx, o));
    if (lane == 0) red[wid] = mx;
    __syncthreads();
    mx = fmaxf(fmaxf(red[0], red[1]), fmaxf(red[2], red[3]));

    float sum = 0.0f;
    for (int d = tid; d < N; d += 256) {
        float e = __expf(C[base + d] - mx);
        C[base + d] = e;
        sum += e;
    }
    for (int o = 32; o; o >>= 1) sum += __shfl_xor(sum, o);
    if (lane == 0) red2[wid] = sum;
    __syncthreads();
    sum = red2[0] + red2[1] + red2[2] + red2[3];
    float inv = 1.0f / sum;
    for (int d = tid; d < N; d += 256) C[base + d] *= inv;
}

// ---------------------------------------------------------------------------
// Launch
// ---------------------------------------------------------------------------
extern "C" void kernel_launch(void* const* d_in, const int* in_sizes, int n_in,
                              void* d_out, int out_size, void* d_ws, size_t ws_size,
                              hipStream_t stream)
{
    const float* X        = (const float*)d_in[0];
    const float* profiles = (const float*)d_in[1];
    const float* ini_embd = (const float*)d_in[2];
    const float* Wa_w     = (const float*)d_in[3];
    const float* Wa_b     = (const float*)d_in[4];
    const float* Ua_w     = (const float*)d_in[5];
    const float* gru_Wih  = (const float*)d_in[6];
    const float* gru_Whh  = (const float*)d_in[7];
    const float* gru_bih  = (const float*)d_in[8];
    const float* gru_bhh  = (const float*)d_in[9];
    const float* tranH_w  = (const float*)d_in[10];
    const float* tranH_b  = (const float*)d_in[11];
    const float* out_w    = (const float*)d_in[12];
    const float* out_b    = (const float*)d_in[13];
    const float* erase_w  = (const float*)d_in[14];
    const float* erase_b  = (const float*)d_in[15];
    const float* add_w    = (const float*)d_in[16];
    const float* add_b    = (const float*)d_in[17];
    const float* iniVam   = (const float*)d_in[18];
    const float* emP_w    = (const float*)d_in[19];
    const float* emP_b    = (const float*)d_in[20];
    const float* attnP_w  = (const float*)d_in[21];
    const float* attnP_b  = (const float*)d_in[22];
    const int* KMIds   = (const int*)d_in[23];
    const int* leaves1 = (const int*)d_in[24];
    const int* anc1    = (const int*)d_in[25];
    const int* leaves2 = (const int*)d_in[26];
    const int* anc2    = (const int*)d_in[27];
    const int* mapInfo = (const int*)d_in[28];
    const int* X_len   = (const int*)d_in[29];

    float* ws = (float*)d_ws;
    float* out = (float*)d_out;

    // ---- workspace layout (floats), with region reuse ----
    const size_t GX_OFF   = 0;                         // 12,582,912 (gx region)
    const size_t PP_OFF   = GX_OFF;                    //   768,000 (early)
    const size_t EMBG_OFF = GX_OFF + 768000;           //   768,000 (early)
    const size_t EMBM_OFF = GX_OFF + 1536000;          //   512,000 (early)
    const size_t SLOT_OFF = GX_OFF;                    // 2,097,152 (late)
    const size_t READ_OFF = GX_OFF + 2097152;          // 2,097,152 (late)
    const size_t F_OFF    = GX_OFF + 4194304;          // 7,340,032 (late)
    const size_t XE_OFF   = 12582912;                  // 4,194,304 (Xe then tran)
    const size_t ERA_OFF  = 16777216;                  // 4,194,304
    const size_t GRU_OFF  = 20971520;                  // 4,194,304
    const size_t PROF_OFF = 25165824;                  //    16,384
    const size_t WHHT_OFF = 25182208;                  //   196,608
    const size_t WIHT_OFF = 25378816;                  //   196,608
    const size_t W2_OFF   = 25575424;                  //    65,536
    const size_t WEA_OFF  = 25640960;                  //    65,536
    const size_t BEA_OFF  = 25706496;                  //       256
    const size_t KMT_OFF  = 25706752;                  //    32,768

    float* PP    = ws + PP_OFF;
    float* embG  = ws + EMBG_OFF;
    float* embM  = ws + EMBM_OFF;
    float* gx    = ws + GX_OFF;
    float* slotw = ws + SLOT_OFF;
    float* readv = ws + READ_OFF;
    float* F     = ws + F_OFF;
    float* Xe    = ws + XE_OFF;
    float* tran  = ws + XE_OFF;
    float* era   = ws + ERA_OFF;
    float* gruo  = ws + GRU_OFF;
    float* prof  = ws + PROF_OFF;
    float* WhhT  = ws + WHHT_OFF;
    float* WihT  = ws + WIHT_OFF;
    float* W2    = ws + W2_OFF;
    float* Wea   = ws + WEA_OFF;
    float* bea   = ws + BEA_OFF;
    float* KMT   = ws + KMT_OFF;

    // ---- prep / pack ----
    k_pack_w2<<<(E_ * 2 * A_ + 255) / 256, 256, 0, stream>>>(Wa_w, W2);
    k_pack_wea<<<(E_ * 2 * V_ + 255) / 256, 256, 0, stream>>>(erase_w, add_w, erase_b, add_b, Wea, bea);
    k_transpose<<<(3 * H_ * E_ + 255) / 256, 256, 0, stream>>>(gru_Wih, WihT, 3 * H_, E_);
    k_transpose<<<(3 * H_ * H_ + 255) / 256, 256, 0, stream>>>(gru_Whh, WhhT, 3 * H_, H_);
    k_kmt<<<(E_ * S_ + 255) / 256, 256, 0, stream>>>(ini_embd, KMIds, KMT);
    k_prof<<<B_, PE_, 0, stream>>>(profiles, emP_w, emP_b, prof);

    dim3 blk(16, 16);

    // ---- PP = ini_embd @ W2 : [3000,256] ----
    {
        dim3 grid((256 + 63) / 64, (TN_ + 63) / 64);
        k_gemm<64, 64, 16, 4, 4, 0, 0><<<grid, blk, 0, stream>>>(
            ini_embd, W2, nullptr, PP, TN_, 2 * A_, E_, nullptr, 0);
    }

    // ---- group attention -> embG [3000,256] ----
    k_group_embed<<<G1N_ + G2N_, 64, 0, stream>>>(PP, Wa_b, Ua_w, ini_embd,
                                                  leaves1, anc1, leaves2, anc2, embG);

    // ---- gather embedMat [2000,256] ----
    k_gather_embed<<<(D_ * E_ + 255) / 256, 256, 0, stream>>>(embG, mapInfo, embM);

    // ---- Xe = X @ embM : [16384,256], K=2000 ----
    {
        dim3 grid(1, M_ / 64);
        k_gemm<64, 256, 16, 4, 16, 0, 0><<<grid, blk, 0, stream>>>(
            X, embM, nullptr, Xe, M_, E_, D_, nullptr, 0);
    }

    // ---- era = sigmoid/tanh(Xe @ Wea + bea) : [16384,256] ----
    {
        dim3 grid(1, M_ / 64);
        k_gemm<64, 256, 16, 4, 16, 0, 1><<<grid, blk, 0, stream>>>(
            Xe, Wea, bea, era, M_, 2 * V_, E_, nullptr, 0);
    }

    // ---- gx = Xe @ WihT + bih : [16384,768] ----
    {
        dim3 grid(3, M_ / 64);
        k_gemm<64, 256, 16, 4, 16, 0, 0><<<grid, blk, 0, stream>>>(
            Xe, WihT, gru_bih, gx, M_, 3 * H_, E_, nullptr, 0);
    }

    // ---- GRU scan -> gruo [16384,256] ----
    k_gru<<<B_ / 4, 256, 0, stream>>>(gx, WhhT, gru_bhh, X_len, gruo);

    // ---- tran = [gruo | prof] @ tranH_w + b : [16384,256], K=320 ----
    {
        dim3 grid(1, M_ / 64);
        k_gemm<64, 256, 16, 4, 16, 1, 0><<<grid, blk, 0, stream>>>(
            gruo, tranH_w, tranH_b, tran, M_, E_, H_ + PE_, prof, H_);
    }

    // ---- slot logits = tran @ KMT : [16384,128] ----
    {
        dim3 grid(S_ / 64, M_ / 64);
        k_gemm<64, 64, 16, 4, 4, 0, 0><<<grid, blk, 0, stream>>>(
            tran, KMT, nullptr, slotw, M_, S_, E_, nullptr, 0);
    }

    // ---- softmax over S ----
    k_softmax128<<<M_, 64, 0, stream>>>(slotw);

    // ---- memory scan -> readv [16384,128] ----
    k_mem<<<B_, 256, 0, stream>>>(slotw, era, iniVam, readv);

    // ---- build F = [gruo | readv | prof2] : [16384,448] ----
    k_build_final<<<M_, 256, 0, stream>>>(gruo, readv, prof, attnP_w, attnP_b, F);

    // ---- logits = F @ out_w + out_b -> d_out [16384,2000] ----
    {
        dim3 grid((D_ + 255) / 256, M_ / 64);
        k_gemm<64, 256, 16, 4, 16, 0, 0><<<grid, blk, 0, stream>>>(
            F, out_w, out_b, out, M_, D_, KF_, nullptr, 0);
    }

    // ---- softmax over D in place ----
    k_softmax_rows<<<M_, 256, 0, stream>>>(out, D_);
}

// Round 3
// 2102.922 us; speedup vs baseline: 1.8815x; 1.8815x over previous
//
#include <hip/hip_runtime.h>
#include <hip/hip_bf16.h>
#include <cmath>

#define T_  64
#define B_  256
#define D_  2000
#define TN_ 3000
#define E_  256
#define H_  256
#define A_  128
#define V_  128
#define PS_ 64
#define PE_ 64
#define S_  128
#define G1N_ 1500
#define G1L_ 4
#define G2N_ 1500
#define G2L_ 6
#define M_  (T_ * B_)
#define KF_ (H_ + V_ + PE_)

typedef __attribute__((ext_vector_type(8))) short short8_t;
typedef __attribute__((ext_vector_type(4))) float floatx4;

static __device__ __forceinline__ float sigmoidf_(float x) {
    return 1.0f / (1.0f + __expf(-x));
}

static __device__ __forceinline__ void bsplit_(float v, __hip_bfloat16& hi, __hip_bfloat16& lo) {
    hi = __float2bfloat16(v);
    lo = __float2bfloat16(v - __bfloat162float(hi));
}

// ---------------------------------------------------------------------------
// Split-bf16 MFMA GEMM: C = A @ B with A ~ Ahi+Alo, B ~ Bhi+Blo (bf16 planes).
// 3 phases: hi*hi + hi*lo + lo*hi accumulated in fp32 -> ~fp32 accuracy.
// B given as BT[Npad][K] row-major (BT[n][k] = B[k][n]); pad rows zeroed.
// M mult of 128; K mult of 32; Npad = nblk*128.
// 256 thr = 4 waves; wave (wm,wn) owns 64x64 = 4x4 frags of 16x16x32.
// LDS fragment-major: frag f at f*512 shorts; lane l owns shorts l*8..l*8+7
// (conflict-free lane-linear ds_read_b128 / ds_write_b128).
// EPI 0: none; 1: sigmoid col<128 else tanh.
// OUTMODE 0: f32 Cf; 1: bf16 split (Chi, Clo). ACCUM: Cf += acc.
// ---------------------------------------------------------------------------
template<int EPI, bool ACCUM, int OUTMODE>
__global__ __launch_bounds__(256)
void k_mgemm3(const __hip_bfloat16* __restrict__ Ahi, const __hip_bfloat16* __restrict__ Alo,
              const __hip_bfloat16* __restrict__ Bhi, const __hip_bfloat16* __restrict__ Blo,
              const float* __restrict__ bias, float* __restrict__ Cf,
              __hip_bfloat16* __restrict__ Chi, __hip_bfloat16* __restrict__ Clo,
              int K, int Nreal, int nblk)
{
    __shared__ __align__(16) short As[4096];
    __shared__ __align__(16) short Bs[4096];

    const int tid  = threadIdx.x;
    const int lane = tid & 63;
    const int w    = tid >> 6;
    const int wm   = w >> 1, wn = w & 1;
    const int lr   = lane & 15;
    const int lkc  = lane >> 4;

    const int bx = blockIdx.x;
    const int m0 = (bx / nblk) * 128;
    const int n0 = (bx % nblk) * 128;

    const int fa = 2 * w;
    const size_t aoff0 = (size_t)(m0 + fa * 16 + lr) * K + lkc * 8;
    const size_t aoff1 = aoff0 + (size_t)16 * K;
    const size_t boff0 = (size_t)(n0 + fa * 16 + lr) * K + lkc * 8;
    const size_t boff1 = boff0 + (size_t)16 * K;

    floatx4 acc[4][4];
#pragma unroll
    for (int i = 0; i < 4; ++i)
#pragma unroll
        for (int j = 0; j < 4; ++j) acc[i][j] = floatx4{0.f, 0.f, 0.f, 0.f};

#pragma unroll 1
    for (int ph = 0; ph < 3; ++ph) {
        const __hip_bfloat16* Ap = (ph == 2) ? Alo : Ahi;
        const __hip_bfloat16* Bp = (ph == 1) ? Blo : Bhi;

        short8_t ra0 = *(const short8_t*)(const void*)(Ap + aoff0);
        short8_t ra1 = *(const short8_t*)(const void*)(Ap + aoff1);
        short8_t rb0 = *(const short8_t*)(const void*)(Bp + boff0);
        short8_t rb1 = *(const short8_t*)(const void*)(Bp + boff1);

        for (int k0 = 0; k0 < K; k0 += 32) {
            __syncthreads();               // LDS safe to overwrite
            *(short8_t*)(void*)&As[(fa    ) * 512 + lane * 8] = ra0;
            *(short8_t*)(void*)&As[(fa + 1) * 512 + lane * 8] = ra1;
            *(short8_t*)(void*)&Bs[(fa    ) * 512 + lane * 8] = rb0;
            *(short8_t*)(void*)&Bs[(fa + 1) * 512 + lane * 8] = rb1;
            __syncthreads();

            if (k0 + 32 < K) {
                int kn = k0 + 32;
                ra0 = *(const short8_t*)(const void*)(Ap + aoff0 + kn);
                ra1 = *(const short8_t*)(const void*)(Ap + aoff1 + kn);
                rb0 = *(const short8_t*)(const void*)(Bp + boff0 + kn);
                rb1 = *(const short8_t*)(const void*)(Bp + boff1 + kn);
            }

            short8_t af[4], bf[4];
#pragma unroll
            for (int i = 0; i < 4; ++i)
                af[i] = *(const short8_t*)(const void*)&As[(wm * 4 + i) * 512 + lane * 8];
#pragma unroll
            for (int j = 0; j < 4; ++j)
                bf[j] = *(const short8_t*)(const void*)&Bs[(wn * 4 + j) * 512 + lane * 8];
#pragma unroll
            for (int i = 0; i < 4; ++i)
#pragma unroll
                for (int j = 0; j < 4; ++j)
                    acc[i][j] = __builtin_amdgcn_mfma_f32_16x16x32_bf16(af[i], bf[j], acc[i][j], 0, 0, 0);
        }
    }

    // C/D layout (m89-verified): col=lane&15, row=(lane>>4)*4+r
#pragma unroll
    for (int i = 0; i < 4; ++i) {
        const int row = m0 + wm * 64 + i * 16 + (lane >> 4) * 4;
#pragma unroll
        for (int j = 0; j < 4; ++j) {
            const int col = n0 + wn * 64 + j * 16 + (lane & 15);
            if (col < Nreal) {
                float bv = bias ? bias[col] : 0.0f;
#pragma unroll
                for (int r = 0; r < 4; ++r) {
                    float v = acc[i][j][r] + bv;
                    if (EPI == 1) v = (col < 128) ? sigmoidf_(v) : tanhf(v);
                    size_t o = (size_t)(row + r) * Nreal + col;
                    if (OUTMODE == 0) {
                        if (ACCUM) v += Cf[o];
                        Cf[o] = v;
                    } else {
                        __hip_bfloat16 h, l;
                        bsplit_(v, h, l);
                        Chi[o] = h; Clo[o] = l;
                    }
                }
            }
        }
    }
}

// ---------------------------------------------------------------------------
// fp32 tiled GEMM (PP = ini_embd @ W2 only) — round-1 proven
// ---------------------------------------------------------------------------
template<int BM, int BN, int BK, int TM, int TN>
__global__ __launch_bounds__(256)
void k_gemm(const float* __restrict__ A, const float* __restrict__ B,
            float* __restrict__ C, int M, int N, int K)
{
    __shared__ float As[BK][BM + 4];
    __shared__ float Bs[BK][BN + 4];
    const int tid = threadIdx.y * blockDim.x + threadIdx.x;
    const int m0 = blockIdx.y * BM;
    const int n0 = blockIdx.x * BN;
    float acc[TM][TN];
#pragma unroll
    for (int i = 0; i < TM; ++i)
#pragma unroll
        for (int j = 0; j < TN; ++j) acc[i][j] = 0.0f;
    for (int k0 = 0; k0 < K; k0 += BK) {
#pragma unroll
        for (int i = tid; i < BM * BK; i += 256) {
            int r = i / BK, c = i % BK;
            int m = m0 + r;
            As[c][r] = (m < M) ? A[(size_t)m * K + k0 + c] : 0.0f;
        }
#pragma unroll
        for (int i = tid; i < BK * BN; i += 256) {
            int r = i / BN, c = i % BN;
            Bs[r][c] = B[(size_t)(k0 + r) * N + n0 + c];
        }
        __syncthreads();
#pragma unroll
        for (int kk = 0; kk < BK; ++kk) {
            float a[TM], b[TN];
#pragma unroll
            for (int i = 0; i < TM; ++i) a[i] = As[kk][threadIdx.y * TM + i];
#pragma unroll
            for (int j = 0; j < TN; ++j) b[j] = Bs[kk][threadIdx.x * TN + j];
#pragma unroll
            for (int i = 0; i < TM; ++i)
#pragma unroll
                for (int j = 0; j < TN; ++j) acc[i][j] += a[i] * b[j];
        }
        __syncthreads();
    }
#pragma unroll
    for (int i = 0; i < TM; ++i) {
        int m = m0 + threadIdx.y * TM + i;
        if (m >= M) continue;
#pragma unroll
        for (int j = 0; j < TN; ++j)
            C[(size_t)m * N + n0 + threadIdx.x * TN + j] = acc[i][j];
    }
}

// ---------------------------------------------------------------------------
// Pack / convert / split kernels
// ---------------------------------------------------------------------------
__global__ void k_pack_w2(const float* __restrict__ Wa_w, float* __restrict__ W2)
{
    int idx = blockIdx.x * blockDim.x + threadIdx.x;
    if (idx >= E_ * 2 * A_) return;
    int e = idx / (2 * A_), j = idx % (2 * A_);
    W2[idx] = (j < A_) ? Wa_w[(size_t)e * A_ + j]
                       : Wa_w[(size_t)(E_ + e) * A_ + (j - A_)];
}

__global__ void k_weaT_split(const float* __restrict__ erase_w, const float* __restrict__ add_w,
                             const float* __restrict__ erase_b, const float* __restrict__ add_b,
                             __hip_bfloat16* __restrict__ Whi, __hip_bfloat16* __restrict__ Wlo,
                             float* __restrict__ bea)
{
    int idx = blockIdx.x * blockDim.x + threadIdx.x;
    if (idx < 256 * 256) {
        int n = idx / 256, k = idx % 256;
        float v = (n < V_) ? erase_w[(size_t)k * V_ + n] : add_w[(size_t)k * V_ + (n - V_)];
        bsplit_(v, Whi[idx], Wlo[idx]);
    }
    if (idx < 2 * V_) bea[idx] = (idx < V_) ? erase_b[idx] : add_b[idx - V_];
}

__global__ void k_wih_split(const float* __restrict__ Wih,
                            __hip_bfloat16* __restrict__ hi, __hip_bfloat16* __restrict__ lo)
{
    int idx = blockIdx.x * blockDim.x + threadIdx.x;
    if (idx < 768 * 256) bsplit_(Wih[idx], hi[idx], lo[idx]);
}

__global__ void k_tranHT_split(const float* __restrict__ tranH_w,
                               __hip_bfloat16* __restrict__ hi, __hip_bfloat16* __restrict__ lo)
{
    int idx = blockIdx.x * blockDim.x + threadIdx.x;
    if (idx >= 256 * 320) return;
    int n = idx / 320, k = idx % 320;
    bsplit_(tranH_w[(size_t)k * 256 + n], hi[idx], lo[idx]);
}

__global__ void k_outWT_split(const float* __restrict__ out_w,
                              __hip_bfloat16* __restrict__ hi, __hip_bfloat16* __restrict__ lo)
{
    int idx = blockIdx.x * blockDim.x + threadIdx.x;
    if (idx >= 2048 * 448) return;
    int n = idx / 448, k = idx % 448;
    float v = (n < D_) ? out_w[(size_t)k * D_ + n] : 0.0f;
    bsplit_(v, hi[idx], lo[idx]);
}

__global__ void k_km_split(const float* __restrict__ ini_embd, const int* __restrict__ KMIds,
                           __hip_bfloat16* __restrict__ hi, __hip_bfloat16* __restrict__ lo)
{
    int idx = blockIdx.x * blockDim.x + threadIdx.x;
    if (idx >= S_ * E_) return;
    int s = idx / E_, k = idx % E_;
    bsplit_(ini_embd[(size_t)KMIds[s] * E_ + k], hi[idx], lo[idx]);
}

// embMT chunk c: dst[e][dd] = embG[mapInfo[c*1024+dd]][e] (0 if d>=2000)
__global__ void k_embMT_chunk(const float* __restrict__ embG, const int* __restrict__ mapInfo,
                              int c, __hip_bfloat16* __restrict__ hi, __hip_bfloat16* __restrict__ lo)
{
    int idx = blockIdx.x * blockDim.x + threadIdx.x;
    if (idx >= 256 * 1024) return;
    int e = idx >> 10, dd = idx & 1023;
    int d = c * 1024 + dd;
    float v = (d < D_) ? embG[(size_t)mapInfo[d] * E_ + e] : 0.0f;
    bsplit_(v, hi[idx], lo[idx]);
}

// X chunk c: dst[m][dd] = X[m][c*1024+dd] split (0 pad)
__global__ void k_x_chunk(const float* __restrict__ X, int c,
                          __hip_bfloat16* __restrict__ hi, __hip_bfloat16* __restrict__ lo)
{
    int idx = blockIdx.x * blockDim.x + threadIdx.x;
    if (idx >= M_ * 1024) return;
    int m = idx >> 10, dd = idx & 1023;
    int d = c * 1024 + dd;
    float v = (d < D_) ? X[(size_t)m * D_ + d] : 0.0f;
    bsplit_(v, hi[idx], lo[idx]);
}

// generic f32 [R*C] -> bf16 split planes
__global__ void k_split_flat(const float* __restrict__ src, int n,
                             __hip_bfloat16* __restrict__ hi, __hip_bfloat16* __restrict__ lo)
{
    int idx = blockIdx.x * blockDim.x + threadIdx.x;
    if (idx < n) bsplit_(src[idx], hi[idx], lo[idx]);
}

__global__ void k_transpose(const float* __restrict__ src, float* __restrict__ dst, int R, int C)
{
    int idx = blockIdx.x * blockDim.x + threadIdx.x;
    if (idx >= R * C) return;
    int r = idx / C, c = idx % C;
    dst[(size_t)c * R + r] = src[idx];
}

__global__ void k_prof(const float* __restrict__ profiles, const float* __restrict__ emP_w,
                       const float* __restrict__ emP_b, float* __restrict__ prof)
{
    int b = blockIdx.x, j = threadIdx.x;
    float acc = emP_b[j];
    for (int k = 0; k < PS_; ++k) acc += profiles[(size_t)b * PS_ + k] * emP_w[(size_t)k * PE_ + j];
    prof[(size_t)b * PE_ + j] = acc;
}

// Atran split cols 256..319 = prof
__global__ void k_fill_tp(const float* __restrict__ prof,
                          __hip_bfloat16* __restrict__ At_hi, __hip_bfloat16* __restrict__ At_lo)
{
    int idx = blockIdx.x * blockDim.x + threadIdx.x;
    if (idx >= M_ * PE_) return;
    int m = idx >> 6, pe = idx & 63;
    float v = prof[(size_t)(m & (B_ - 1)) * PE_ + pe];
    size_t o = (size_t)m * 320 + 256 + pe;
    bsplit_(v, At_hi[o], At_lo[o]);
}

// ---------------------------------------------------------------------------
// GRAM group attention (round-1 proven)
// ---------------------------------------------------------------------------
__global__ void k_group_embed(const float* __restrict__ PP, const float* __restrict__ Wa_b,
                              const float* __restrict__ Ua_w, const float* __restrict__ ini_embd,
                              const int* __restrict__ leaves1, const int* __restrict__ anc1,
                              const int* __restrict__ leaves2, const int* __restrict__ anc2,
                              float* __restrict__ embedG)
{
    int n = blockIdx.x;
    int lane = threadIdx.x;
    const int* lv; const int* ac; int L;
    if (n < G1N_) { L = G1L_; lv = leaves1 + (size_t)n * G1L_; ac = anc1 + (size_t)n * G1L_; }
    else { int n2 = n - G1N_; L = G2L_; lv = leaves2 + (size_t)n2 * G2L_; ac = anc2 + (size_t)n2 * G2L_; }

    float score[6]; int ai[6];
    for (int l = 0; l < L; ++l) {
        int li = lv[l]; int av = ac[l]; ai[l] = av;
        float s = 0.0f;
        for (int a = lane; a < A_; a += 64) {
            float hv = tanhf(PP[(size_t)li * 256 + a] + PP[(size_t)av * 256 + 128 + a] + Wa_b[a]);
            s += hv * Ua_w[a];
        }
        for (int o = 32; o; o >>= 1) s += __shfl_xor(s, o);
        score[l] = s;
    }
    float mx = -1e30f;
    for (int l = 0; l < L; ++l) mx = fmaxf(mx, score[l]);
    float w[6], sum = 0.0f;
    for (int l = 0; l < L; ++l) { w[l] = __expf(score[l] - mx); sum += w[l]; }
    float inv = 1.0f / sum;
    for (int e = lane; e < E_; e += 64) {
        float acc = 0.0f;
        for (int l = 0; l < L; ++l) acc += w[l] * inv * ini_embd[(size_t)ai[l] * E_ + e];
        embedG[(size_t)n * E_ + e] = acc;
    }
}

// ---------------------------------------------------------------------------
// GRU scan (round-1 proven fp32) + split h stores for tran A-operand
// ---------------------------------------------------------------------------
__global__ __launch_bounds__(256)
void k_gru(const float* __restrict__ gx, const float* __restrict__ WhhT,
           const float* __restrict__ bhh, const int* __restrict__ X_len,
           float* __restrict__ gruo,
           __hip_bfloat16* __restrict__ At_hi, __hip_bfloat16* __restrict__ At_lo)
{
    const int wg = blockIdx.x;
    const int s0 = wg * 4;
    const int tid = threadIdx.x;
    __shared__ float h[4][H_];

#pragma unroll
    for (int s = 0; s < 4; ++s) h[s][tid] = 0.0f;
    int len[4];
#pragma unroll
    for (int s = 0; s < 4; ++s) len[s] = X_len[s0 + s];
    __syncthreads();

    const float b0 = bhh[tid], b1 = bhh[256 + tid], b2 = bhh[512 + tid];

    for (int t = 0; t < T_; ++t) {
        float acc[4][3];
#pragma unroll
        for (int s = 0; s < 4; ++s) { acc[s][0] = b0; acc[s][1] = b1; acc[s][2] = b2; }

#pragma unroll 4
        for (int e = 0; e < H_; ++e) {
            const float* wr = WhhT + (size_t)e * (3 * H_);
            float w0 = wr[tid], w1 = wr[256 + tid], w2 = wr[512 + tid];
            float h0 = h[0][e], h1 = h[1][e], h2 = h[2][e], h3 = h[3][e];
            acc[0][0] += h0 * w0; acc[0][1] += h0 * w1; acc[0][2] += h0 * w2;
            acc[1][0] += h1 * w0; acc[1][1] += h1 * w1; acc[1][2] += h1 * w2;
            acc[2][0] += h2 * w0; acc[2][1] += h2 * w1; acc[2][2] += h2 * w2;
            acc[3][0] += h3 * w0; acc[3][1] += h3 * w1; acc[3][2] += h3 * w2;
        }

        float hst[4], ost[4];
#pragma unroll
        for (int s = 0; s < 4; ++s) {
            size_t gb = ((size_t)t * B_ + (s0 + s)) * (3 * H_);
            float r  = sigmoidf_(gx[gb + tid] + acc[s][0]);
            float z  = sigmoidf_(gx[gb + 256 + tid] + acc[s][1]);
            float nn = tanhf(gx[gb + 512 + tid] + r * acc[s][2]);
            float hold = h[s][tid];
            float hnew = (1.0f - z) * nn + z * hold;
            bool msk = (t < len[s]);
            float hv = msk ? hnew : hold;
            hst[s] = hv;
            ost[s] = msk ? hv : 0.0f;
        }
        __syncthreads();
#pragma unroll
        for (int s = 0; s < 4; ++s) {
            h[s][tid] = hst[s];
            size_t m = (size_t)t * B_ + (s0 + s);
            gruo[m * H_ + tid] = ost[s];
            size_t o = m * 320 + tid;
            bsplit_(ost[s], At_hi[o], At_lo[o]);
        }
        __syncthreads();
    }
}

// ---------------------------------------------------------------------------
// Value-memory scan (round-1 proven)
// ---------------------------------------------------------------------------
__global__ __launch_bounds__(256)
void k_mem(const float* __restrict__ slotw, const float* __restrict__ era,
           const float* __restrict__ iniVam, float* __restrict__ readv)
{
    const int b = blockIdx.x;
    const int tid = threadIdx.x;
    const int v = tid & (V_ - 1);
    const int sh = tid >> 7;
    const int sbase = sh * 64;

    float VM[64];
#pragma unroll 8
    for (int i = 0; i < 64; ++i) VM[i] = iniVam[(size_t)(sbase + i) * V_ + v];

    __shared__ float swL[S_];
    __shared__ float eaL[2 * V_];
    __shared__ float part[V_];

    for (int t = 0; t < T_; ++t) {
        size_t m = (size_t)t * B_ + b;
        if (tid < S_) swL[tid] = slotw[m * S_ + tid];
        eaL[tid] = era[m * (2 * V_) + tid];
        __syncthreads();

        float er = eaL[v], ad = eaL[V_ + v];
        float acc = 0.0f;
#pragma unroll 8
        for (int i = 0; i < 64; ++i) {
            float sv = swL[sbase + i];
            float vm = VM[i];
            acc += sv * vm;
            VM[i] = vm * (1.0f - sv * er) + sv * ad;
        }
        if (sh == 1) part[v] = acc;
        __syncthreads();
        if (sh == 0) readv[m * V_ + v] = acc + part[v];
        __syncthreads();
    }
}

// ---------------------------------------------------------------------------
// F = [gruo | read | prof2] as bf16 split planes
// ---------------------------------------------------------------------------
__global__ __launch_bounds__(256)
void k_build_final(const float* __restrict__ gruo, const float* __restrict__ readv,
                   const float* __restrict__ prof, const float* __restrict__ attnP_w,
                   const float* __restrict__ attnP_b,
                   __hip_bfloat16* __restrict__ F_hi, __hip_bfloat16* __restrict__ F_lo)
{
    const int m = blockIdx.x;
    const int b = m & (B_ - 1);
    const int tid = threadIdx.x;
    __shared__ float rd[V_];
    __shared__ float pf[PE_];
    if (tid < V_) rd[tid] = readv[(size_t)m * V_ + tid];
    if (tid < PE_) pf[tid] = prof[(size_t)b * PE_ + tid];
    __syncthreads();

    size_t base = (size_t)m * KF_;
    bsplit_(gruo[(size_t)m * H_ + tid], F_hi[base + tid], F_lo[base + tid]);
    if (tid < V_) bsplit_(rd[tid], F_hi[base + H_ + tid], F_lo[base + H_ + tid]);
    if (tid < PE_) {
        float a = attnP_b[tid];
        for (int k = 0; k < PE_; ++k) a += pf[k] * attnP_w[(size_t)k * PE_ + tid];
        for (int k = 0; k < V_; ++k) a += rd[k] * attnP_w[(size_t)(PE_ + k) * PE_ + tid];
        a = fmaxf(a, 0.0f);
        bsplit_(pf[tid] * a, F_hi[base + H_ + V_ + tid], F_lo[base + H_ + V_ + tid]);
    }
}

// ---------------------------------------------------------------------------
// Softmaxes
// ---------------------------------------------------------------------------
__global__ void k_softmax128(float* __restrict__ C)
{
    const int m = blockIdx.x;
    const size_t base = (size_t)m * S_;
    const int lane = threadIdx.x;
    float a = C[base + lane], b = C[base + 64 + lane];
    float mx = fmaxf(a, b);
    for (int o = 32; o; o >>= 1) mx = fmaxf(mx, __shfl_xor(mx, o));
    float e0 = __expf(a - mx), e1 = __expf(b - mx);
    float s = e0 + e1;
    for (int o = 32; o; o >>= 1) s += __shfl_xor(s, o);
    float inv = 1.0f / s;
    C[base + lane] = e0 * inv;
    C[base + 64 + lane] = e1 * inv;
}

__global__ __launch_bounds__(256)
void k_softmax2000(float* __restrict__ C)
{
    const int m = blockIdx.x;
    const size_t base = (size_t)m * D_;
    const int tid = threadIdx.x;
    const int wid = tid >> 6, lane = tid & 63;
    __shared__ float red[4], red2[4];

    float v[8];
#pragma unroll
    for (int i = 0; i < 8; ++i) {
        int d = i * 256 + tid;
        v[i] = (d < D_) ? C[base + d] : -1e30f;
    }
    float mx = v[0];
#pragma unroll
    for (int i = 1; i < 8; ++i) mx = fmaxf(mx, v[i]);
    for (int o = 32; o; o >>= 1) mx = fmaxf(mx, __shfl_xor(mx, o));
    if (lane == 0) red[wid] = mx;
    __syncthreads();
    mx = fmaxf(fmaxf(red[0], red[1]), fmaxf(red[2], red[3]));

    float sum = 0.0f;
#pragma unroll
    for (int i = 0; i < 8; ++i) { v[i] = __expf(v[i] - mx); sum += v[i]; }
    for (int o = 32; o; o >>= 1) sum += __shfl_xor(sum, o);
    if (lane == 0) red2[wid] = sum;
    __syncthreads();
    sum = red2[0] + red2[1] + red2[2] + red2[3];
    float inv = 1.0f / sum;
#pragma unroll
    for (int i = 0; i < 8; ++i) {
        int d = i * 256 + tid;
        if (d < D_) C[base + d] = v[i] * inv;
    }
}

// ---------------------------------------------------------------------------
// Launch
// ---------------------------------------------------------------------------
extern "C" void kernel_launch(void* const* d_in, const int* in_sizes, int n_in,
                              void* d_out, int out_size, void* d_ws, size_t ws_size,
                              hipStream_t stream)
{
    const float* X        = (const float*)d_in[0];
    const float* profiles = (const float*)d_in[1];
    const float* ini_embd = (const float*)d_in[2];
    const float* Wa_w     = (const float*)d_in[3];
    const float* Wa_b     = (const float*)d_in[4];
    const float* Ua_w     = (const float*)d_in[5];
    const float* gru_Wih  = (const float*)d_in[6];
    const float* gru_Whh  = (const float*)d_in[7];
    const float* gru_bih  = (const float*)d_in[8];
    const float* gru_bhh  = (const float*)d_in[9];
    const float* tranH_w  = (const float*)d_in[10];
    const float* tranH_b  = (const float*)d_in[11];
    const float* out_w    = (const float*)d_in[12];
    const float* out_b    = (const float*)d_in[13];
    const float* erase_w  = (const float*)d_in[14];
    const float* erase_b  = (const float*)d_in[15];
    const float* add_w    = (const float*)d_in[16];
    const float* add_b    = (const float*)d_in[17];
    const float* iniVam   = (const float*)d_in[18];
    const float* emP_w    = (const float*)d_in[19];
    const float* emP_b    = (const float*)d_in[20];
    const float* attnP_w  = (const float*)d_in[21];
    const float* attnP_b  = (const float*)d_in[22];
    const int* KMIds   = (const int*)d_in[23];
    const int* leaves1 = (const int*)d_in[24];
    const int* anc1    = (const int*)d_in[25];
    const int* leaves2 = (const int*)d_in[26];
    const int* anc2    = (const int*)d_in[27];
    const int* mapInfo = (const int*)d_in[28];
    const int* X_len   = (const int*)d_in[29];

    char* ws = (char*)d_ws;
    float* out = (float*)d_out;
    typedef __hip_bfloat16 bf16;

    // ---- workspace layout (bytes), total 130,024,448 (~124 MiB) ----
    const size_t R0 = 0;            // 67,108,864
    //   early: PP f32 @0 (12,288,000), embG f32 @12,288,000 (12,288,000)
    //   Xe phase: Xc_hi @0 (33,554,432), Xc_lo @33,554,432 (33,554,432)
    //   gx phase: gx f32 @0 (50,331,648), Xe_hi @50,331,648 (8,388,608), Xe_lo @58,720,256
    //   tran phase: tran_hi @0 (8,388,608), tran_lo @8,388,608
    //   final: F_hi @0 (14,680,064), F_lo @14,680,064
    const size_t R1 = 67108864;     // 16,777,216 : Xe f32; later gruo f32
    const size_t R2 = 83886080;     // 16,777,216 : era f32
    const size_t R3 = 100663296;    // 20,971,520 : Atran_hi @0 (10,485,760), Atran_lo @10,485,760
    //   later: slotw f32 @0 (8,388,608), readv f32 @10,485,760 (8,388,608)
    size_t P = 121634816;
    const size_t E0HI = P; P += 524288;   // embMT chunk0 hi [256][1024]
    const size_t E0LO = P; P += 524288;
    const size_t E1HI = P; P += 524288;
    const size_t E1LO = P; P += 524288;
    const size_t OWHI = P; P += 1835008;  // outWT hi [2048][448]
    const size_t OWLO = P; P += 1835008;
    const size_t WIHI = P; P += 393216;   // Wih hi [768][256]
    const size_t WILO = P; P += 393216;
    const size_t WEHI = P; P += 131072;   // WeaT hi [256][256]
    const size_t WELO = P; P += 131072;
    const size_t THHI = P; P += 163840;   // tranHT hi [256][320]
    const size_t THLO = P; P += 163840;
    const size_t KMHI = P; P += 65536;    // KM hi [128][256]
    const size_t KMLO = P; P += 65536;
    const size_t WHHT = P; P += 786432;   // WhhT f32 [256][768]
    const size_t PROF = P; P += 65536;
    const size_t BEA  = P; P += 1024;
    const size_t W2O  = P; P += 262144;

    float* PP      = (float*)(ws + R0);
    float* embG    = (float*)(ws + R0 + 12288000);
    bf16*  Xc_hi   = (bf16*)(ws + R0);
    bf16*  Xc_lo   = (bf16*)(ws + R0 + 33554432);
    float* gx      = (float*)(ws + R0);
    bf16*  Xe_hi   = (bf16*)(ws + R0 + 50331648);
    bf16*  Xe_lo   = (bf16*)(ws + R0 + 58720256);
    bf16*  tran_hi = (bf16*)(ws + R0);
    bf16*  tran_lo = (bf16*)(ws + R0 + 8388608);
    bf16*  F_hi    = (bf16*)(ws + R0);
    bf16*  F_lo    = (bf16*)(ws + R0 + 14680064);
    float* Xe_f    = (float*)(ws + R1);
    float* gruo    = (float*)(ws + R1);
    float* era     = (float*)(ws + R2);
    bf16*  At_hi   = (bf16*)(ws + R3);
    bf16*  At_lo   = (bf16*)(ws + R3 + 10485760);
    float* slotw   = (float*)(ws + R3);
    float* readv   = (float*)(ws + R3 + 10485760);
    bf16*  E0hi = (bf16*)(ws + E0HI); bf16* E0lo = (bf16*)(ws + E0LO);
    bf16*  E1hi = (bf16*)(ws + E1HI); bf16* E1lo = (bf16*)(ws + E1LO);
    bf16*  OWhi = (bf16*)(ws + OWHI); bf16* OWlo = (bf16*)(ws + OWLO);
    bf16*  WIhi = (bf16*)(ws + WIHI); bf16* WIlo = (bf16*)(ws + WILO);
    bf16*  WEhi = (bf16*)(ws + WEHI); bf16* WElo = (bf16*)(ws + WELO);
    bf16*  THhi = (bf16*)(ws + THHI); bf16* THlo = (bf16*)(ws + THLO);
    bf16*  KMhi = (bf16*)(ws + KMHI); bf16* KMlo = (bf16*)(ws + KMLO);
    float* WhhT = (float*)(ws + WHHT);
    float* prof = (float*)(ws + PROF);
    float* bea  = (float*)(ws + BEA);
    float* W2p  = (float*)(ws + W2O);

    // ---- weight packs ----
    k_pack_w2<<<(E_ * 2 * A_ + 255) / 256, 256, 0, stream>>>(Wa_w, W2p);
    k_weaT_split<<<(256 * 256 + 255) / 256, 256, 0, stream>>>(erase_w, add_w, erase_b, add_b, WEhi, WElo, bea);
    k_wih_split<<<(768 * 256 + 255) / 256, 256, 0, stream>>>(gru_Wih, WIhi, WIlo);
    k_tranHT_split<<<(256 * 320 + 255) / 256, 256, 0, stream>>>(tranH_w, THhi, THlo);
    k_outWT_split<<<(2048 * 448 + 255) / 256, 256, 0, stream>>>(out_w, OWhi, OWlo);
    k_km_split<<<(S_ * E_ + 255) / 256, 256, 0, stream>>>(ini_embd, KMIds, KMhi, KMlo);
    k_transpose<<<(3 * H_ * H_ + 255) / 256, 256, 0, stream>>>(gru_Whh, WhhT, 3 * H_, H_);
    k_prof<<<B_, PE_, 0, stream>>>(profiles, emP_w, emP_b, prof);

    // ---- ontology attention -> embedMat (chunked BT, split) ----
    {
        dim3 blk(16, 16);
        dim3 grid(4, (TN_ + 63) / 64);
        k_gemm<64, 64, 16, 4, 4><<<grid, blk, 0, stream>>>(ini_embd, W2p, PP, TN_, 256, E_);
    }
    k_group_embed<<<G1N_ + G2N_, 64, 0, stream>>>(PP, Wa_b, Ua_w, ini_embd,
                                                  leaves1, anc1, leaves2, anc2, embG);
    k_embMT_chunk<<<(256 * 1024) / 256, 256, 0, stream>>>(embG, mapInfo, 0, E0hi, E0lo);
    k_embMT_chunk<<<(256 * 1024) / 256, 256, 0, stream>>>(embG, mapInfo, 1, E1hi, E1lo);

    // ---- Xe = X @ embM (split, K-chunked 2x1024, fp32 accumulate) ----
    k_x_chunk<<<(M_ * 1024) / 256, 256, 0, stream>>>(X, 0, Xc_hi, Xc_lo);
    k_mgemm3<0, false, 0><<<128 * 2, 256, 0, stream>>>(Xc_hi, Xc_lo, E0hi, E0lo,
        nullptr, Xe_f, nullptr, nullptr, 1024, 256, 2);
    k_x_chunk<<<(M_ * 1024) / 256, 256, 0, stream>>>(X, 1, Xc_hi, Xc_lo);
    k_mgemm3<0, true, 0><<<128 * 2, 256, 0, stream>>>(Xc_hi, Xc_lo, E1hi, E1lo,
        nullptr, Xe_f, nullptr, nullptr, 1024, 256, 2);

    // Xe f32 -> split planes (Xc region is dead now)
    k_split_flat<<<(M_ * 256) / 256, 256, 0, stream>>>(Xe_f, M_ * 256, Xe_hi, Xe_lo);

    // ---- era = gates(Xe @ Wea + bea) ----
    k_mgemm3<1, false, 0><<<128 * 2, 256, 0, stream>>>(Xe_hi, Xe_lo, WEhi, WElo,
        bea, era, nullptr, nullptr, 256, 256, 2);

    // ---- gx = Xe @ Wih^T + bih ----
    k_mgemm3<0, false, 0><<<128 * 6, 256, 0, stream>>>(Xe_hi, Xe_lo, WIhi, WIlo,
        gru_bih, gx, nullptr, nullptr, 256, 768, 6);

    // ---- GRU scan ----
    k_gru<<<B_ / 4, 256, 0, stream>>>(gx, WhhT, gru_bhh, X_len, gruo, At_hi, At_lo);
    k_fill_tp<<<(M_ * PE_) / 256, 256, 0, stream>>>(prof, At_hi, At_lo);

    // ---- tran = [gruo|prof] @ tranH + b (split out) ----
    k_mgemm3<0, false, 1><<<128 * 2, 256, 0, stream>>>(At_hi, At_lo, THhi, THlo,
        tranH_b, nullptr, tran_hi, tran_lo, 320, 256, 2);

    // ---- slot logits = tran @ KM^T ----
    k_mgemm3<0, false, 0><<<128 * 1, 256, 0, stream>>>(tran_hi, tran_lo, KMhi, KMlo,
        nullptr, slotw, nullptr, nullptr, 256, 128, 1);

    k_softmax128<<<M_, 64, 0, stream>>>(slotw);
    k_mem<<<B_, 256, 0, stream>>>(slotw, era, iniVam, readv);
    k_build_final<<<M_, 256, 0, stream>>>(gruo, readv, prof, attnP_w, attnP_b, F_hi, F_lo);

    // ---- logits = F @ out_w + out_b ----
    k_mgemm3<0, false, 0><<<128 * 16, 256, 0, stream>>>(F_hi, F_lo, OWhi, OWlo,
        out_b, out, nullptr, nullptr, 448, 2000, 16);

    k_softmax2000<<<M_, 256, 0, stream>>>(out);
}